// Round 8
// baseline (56.802 us; speedup 1.0000x reference)
//
#include <hip/hip_runtime.h>

#define HH 256
#define WW 256
#define PLANE (HH * WW)          // 65536
#define CORE 32                  // output rows per strip (8 strips per image)
#define HALO 16                  // temporal halo rows (>= steps per launch)
#define NW 16                    // waves per block (1024 threads)
#define KSTEP 2                  // steps per barrier round

// Horizontal neighbor exchange on the VALU pipe via gfx9 DPP wave shifts.
// bound_ctrl zero-fill gives the image-border zero-pad for free at lanes 0/63.
__device__ __forceinline__ float dpp_shfl_up1(float x) {   // lane i <- lane i-1; lane 0 <- 0
    return __int_as_float(__builtin_amdgcn_update_dpp(
        0, __float_as_int(x), 0x138 /*wave_shr:1*/, 0xf, 0xf, true));
}
__device__ __forceinline__ float dpp_shfl_dn1(float x) {   // lane i <- lane i+1; lane 63 <- 0
    return __int_as_float(__builtin_amdgcn_update_dpp(
        0, __float_as_int(x), 0x130 /*wave_shl:1*/, 0xf, 0xf, true));
}

// One trapezoid sub-step over local rows [LO, HI] (compile-time -> static
// register indexing). Row r reads old rows r-1 (rolling carry), r, r+1.
template<int LO, int HI>
__device__ __forceinline__ void step_range(float (&u)[8][4],
                                           const float (&pD)[6][4],
                                           const float (&pR)[6][4]) {
    float carry[4];
    #pragma unroll
    for (int c = 0; c < 4; ++c) carry[c] = u[LO - 1][c];
    #pragma unroll
    for (int r = LO; r <= HI; ++r) {
        const float lf = dpp_shfl_up1(u[r][3]);
        const float rt = dpp_shfl_dn1(u[r][0]);
        float old[4];
        #pragma unroll
        for (int c = 0; c < 4; ++c) old[c] = u[r][c];
        #pragma unroll
        for (int c = 0; c < 4; ++c) {
            const float upv = carry[c];
            const float dnv = u[r + 1][c];           // not yet rewritten this sub-step
            const float lv  = c ? old[c - 1] : lf;
            const float rv  = (c < 3) ? old[c + 1] : rt;
            const float uc  = old[c];
            const float s4  = (upv + dnv) + (lv + rv);
            const float lap = fmaf(-4.0f, uc, s4);
            const float g   = fmaf(-uc, uc, uc);     // uc*(1-uc)
            const float a   = fmaf(pD[r - 1][c], lap, uc);
            const float nv  = fmaf(pR[r - 1][c], g, a);
            u[r][c] = __builtin_amdgcn_fmed3f(nv, 0.0f, 1.0f);
        }
        #pragma unroll
        for (int c = 0; c < 4; ++c) carry[c] = old[c];
    }
}

// R8 structure: k=2 temporal blocking per barrier round -> 8 rounds per
// 16-step launch instead of 16 barrier-steps. Each wave owns 4 core rows
// (local 2..5) + 2-row halo each side (0,1 and 6,7). Per round: publish core
// rows to double-buffered LDS -> ONE barrier -> refresh halos from neighbors
// -> step A on rows 1..6, step B on rows 2..5 (shrinking trapezoid, exactness
// telescopes). Neighbor map: my rows 0,1 = (w-1)'s rows 4,5; my rows 6,7 =
// (w+1)'s rows 2,3. Trapezoid skip at round granularity via
// jend = my_steps - s0; stale values only land where need(row) < step.
// Rows with dist >= ls keep pD=pR=0 -> pass-through (and out-of-image rows
// stay 0 = conv zero-pad).
__global__ __launch_bounds__(1024, 4)
void rd_round_kernel(const float* __restrict__ uin,
                     const float* __restrict__ params,
                     const int* __restrict__ t,
                     float* __restrict__ uout,
                     int base, int ktot)
{
    __shared__ float4 pub[2][NW][4][64];   // each wave's core rows 2..5; 128 KB

    const int blk   = blockIdx.x;
    const int b     = blk >> 3;            // image (8 strips per image)
    const int strip = blk & 7;
    const int r0    = strip * CORE;
    const int w     = threadIdx.x >> 6;    // wave = row-group, 0..15
    const int lane  = threadIdx.x & 63;    // lane = col-group (4 cols each)
    const int c0    = lane << 2;

    int ls = t[b] - base;
    ls = ls < 0 ? 0 : (ls > ktot ? ktot : ls);

    // distance of wave's core rows (slab-local 4w..4w+3) from band 16..47
    int tg = 16 - (4 * w + 3), bg = 4 * w - 47;
    int d_min = tg > bg ? tg : bg;
    if (d_min < 0) d_min = 0;
    int my_steps = ls - d_min;
    if (my_steps < 0) my_steps = 0;

    const int base_row = r0 - HALO + 4 * w;   // global row of local L=2
    const size_t ubase = (size_t)b * PLANE;
    const size_t pbase = (size_t)b * 2 * PLANE;

    float u[8][4], pD[6][4], pR[6][4];

    #pragma unroll
    for (int L = 0; L < 8; ++L)
        #pragma unroll
        for (int c = 0; c < 4; ++c) u[L][c] = 0.f;

    // load only core rows 2..5 (halos come from neighbors' round-0 publish;
    // edge waves' halos are beyond distance 16 and never needed)
    #pragma unroll
    for (int L = 2; L <= 5; ++L) {
        const int grow = base_row + (L - 2);
        int dist = 0;
        if (grow < r0)                 dist = r0 - grow;
        else if (grow > r0 + CORE - 1) dist = grow - (r0 + CORE - 1);
        if (grow >= 0 && grow < HH && dist <= ls) {
            const float4 uu = *reinterpret_cast<const float4*>(uin + ubase + (size_t)grow * WW + c0);
            u[L][0] = uu.x; u[L][1] = uu.y; u[L][2] = uu.z; u[L][3] = uu.w;
        }
    }
    // params for all computed rows 1..6 (gated: only rows that truly step)
    #pragma unroll
    for (int L = 1; L <= 6; ++L) {
        const int grow = base_row + (L - 2);
        int dist = 0;
        if (grow < r0)                 dist = r0 - grow;
        else if (grow > r0 + CORE - 1) dist = grow - (r0 + CORE - 1);
        if (grow >= 0 && grow < HH && dist < ls) {
            const float4 dd = *reinterpret_cast<const float4*>(params + pbase + (size_t)grow * WW + c0);
            const float4 rr = *reinterpret_cast<const float4*>(params + pbase + PLANE + (size_t)grow * WW + c0);
            pD[L-1][0] = dd.x; pD[L-1][1] = dd.y; pD[L-1][2] = dd.z; pD[L-1][3] = dd.w;
            pR[L-1][0] = rr.x; pR[L-1][1] = rr.y; pR[L-1][2] = rr.z; pR[L-1][3] = rr.w;
        } else {
            pD[L-1][0] = pD[L-1][1] = pD[L-1][2] = pD[L-1][3] = 0.f;
            pR[L-1][0] = pR[L-1][1] = pR[L-1][2] = pR[L-1][3] = 0.f;
        }
    }

    int bufi = 0;
    for (int s0 = 0; s0 < ls; s0 += KSTEP) {   // ls is block-uniform
        // publish current core rows 2..5
        pub[bufi][w][0][lane] = make_float4(u[2][0], u[2][1], u[2][2], u[2][3]);
        pub[bufi][w][1][lane] = make_float4(u[3][0], u[3][1], u[3][2], u[3][3]);
        pub[bufi][w][2][lane] = make_float4(u[4][0], u[4][1], u[4][2], u[4][3]);
        pub[bufi][w][3][lane] = make_float4(u[5][0], u[5][1], u[5][2], u[5][3]);
        __syncthreads();
        if (w > 0) {                    // my rows 0,1 = (w-1)'s rows 4,5
            const float4 a = pub[bufi][w-1][2][lane];
            const float4 q = pub[bufi][w-1][3][lane];
            u[0][0]=a.x; u[0][1]=a.y; u[0][2]=a.z; u[0][3]=a.w;
            u[1][0]=q.x; u[1][1]=q.y; u[1][2]=q.z; u[1][3]=q.w;
        }
        if (w < NW - 1) {               // my rows 6,7 = (w+1)'s rows 2,3
            const float4 a = pub[bufi][w+1][0][lane];
            const float4 q = pub[bufi][w+1][1][lane];
            u[6][0]=a.x; u[6][1]=a.y; u[6][2]=a.z; u[6][3]=a.w;
            u[7][0]=q.x; u[7][1]=q.y; u[7][2]=q.z; u[7][3]=q.w;
        }
        bufi ^= 1;

        const int jend = my_steps - s0;            // wave-uniform
        if (jend >= 1) step_range<1, 6>(u, pD, pR);   // step s0
        if (jend >= 2) step_range<2, 5>(u, pD, pR);   // step s0+1
    }

    // write back core rows (waves 4..11 carry the output band)
    #pragma unroll
    for (int L = 2; L <= 5; ++L) {
        const int grow = base_row + (L - 2);
        if (grow >= r0 && grow < r0 + CORE) {
            *reinterpret_cast<float4*>(uout + ubase + (size_t)grow * WW + c0) =
                make_float4(u[L][0], u[L][1], u[L][2], u[L][3]);
        }
    }
}

extern "C" void kernel_launch(void* const* d_in, const int* in_sizes, int n_in,
                              void* d_out, int out_size, void* d_ws, size_t ws_size,
                              hipStream_t stream) {
    (void)in_sizes; (void)n_in; (void)out_size; (void)ws_size;
    const float* u      = (const float*)d_in[0];
    const float* params = (const float*)d_in[1];
    const int*   t      = (const int*)d_in[2];
    float*       out    = (float*)d_out;
    float*       ws     = (float*)d_ws;

    const dim3 grid(256), block(1024);
    // steps [0,16) -> ws, steps [16,31) -> out
    rd_round_kernel<<<grid, block, 0, stream>>>(u,  params, t, ws,  0,  16);
    rd_round_kernel<<<grid, block, 0, stream>>>(ws, params, t, out, 16, 15);
}

// Round 9
// 51.962 us; speedup vs baseline: 1.0931x; 1.0931x over previous
//
#include <hip/hip_runtime.h>

#define HH 256
#define WW 256
#define PLANE (HH * WW)          // 65536
#define CORE 16                  // output rows per strip (16 strips per image)
#define HALO 16                  // temporal halo rows (>= steps per launch)
#define SLAB 48                  // CORE + 2*HALO
#define NW 16                    // waves per block (1024 threads)
#define RPW 3                    // slab rows per wave (SLAB / NW) -> 12 cells/thread

// Horizontal neighbor exchange on the VALU pipe via gfx9 DPP wave shifts.
// bound_ctrl zero-fill gives the image-border zero-pad for free at lanes 0/63.
__device__ __forceinline__ float dpp_shfl_up1(float x) {   // lane i <- lane i-1; lane 0 <- 0
    return __int_as_float(__builtin_amdgcn_update_dpp(
        0, __float_as_int(x), 0x138 /*wave_shr:1*/, 0xf, 0xf, true));
}
__device__ __forceinline__ float dpp_shfl_dn1(float x) {   // lane i <- lane i+1; lane 63 <- 0
    return __int_as_float(__builtin_amdgcn_update_dpp(
        0, __float_as_int(x), 0x130 /*wave_shl:1*/, 0xf, 0xf, true));
}

// R9: 512 blocks x 1024 threads = 524K threads -> 2 blocks/CU, 32 waves/CU
// (8 waves/SIMD, the full wave-slot budget). Requires VGPR <= 64: RPW=3
// keeps live arrays at 36 floats (u12+D12+R12), enforced by
// __launch_bounds__(1024, 8). Per-thread work drops to 12 cells/step
// (R3-R8 carried 16-24, and R5/R8 spilled at VGPR=64).
// One block = one 48-row slab (16-row core + 16-row halo) of one image.
// Vertical neighbors via double-buffered LDS boundary rows, ONE barrier/step;
// horizontal via DPP. Trapezoid: wave w runs my_steps = max(0, ls - d_min(w))
// (wave-uniform); stale rows land only in the reader's don't-care region.
// Rows at distance d from the core load u only if d <= ls, params if d < ls;
// unloaded rows are 0 with D=rho=0 and stay 0 (= conv zero-pad).
__global__ __launch_bounds__(1024, 8)
void rd_occ_kernel(const float* __restrict__ uin,
                   const float* __restrict__ params,
                   const int* __restrict__ t,
                   float* __restrict__ uout,
                   int base, int k)
{
    __shared__ float4 vt[2][NW][64];   // each wave's top row (dr=0)      32 KB
    __shared__ float4 vb[2][NW][64];   // each wave's bottom row (dr=2)   32 KB

    const int blk   = blockIdx.x;
    const int b     = blk >> 4;          // image index (16 strips per image)
    const int strip = blk & 15;
    const int r0    = strip * CORE;
    const int w     = threadIdx.x >> 6;  // wave = row-group, 0..15
    const int lane  = threadIdx.x & 63;  // lane = col-group (4 cols each)
    const int c0    = lane << 2;

    int ls = t[b] - base;
    ls = ls < 0 ? 0 : (ls > k ? k : ls);

    // wave's closest-row distance from the core slab band [HALO, HALO+CORE-1]
    const int top_gap = HALO - (RPW * w + RPW - 1);
    const int bot_gap = RPW * w - (HALO + CORE - 1);
    int d_min = top_gap > bot_gap ? top_gap : bot_gap;
    if (d_min < 0) d_min = 0;
    int my_steps = ls - d_min;
    if (my_steps < 0) my_steps = 0;

    const int growbase = r0 - HALO + RPW * w;  // global row of this thread's dr=0
    const size_t ubase = (size_t)b * PLANE;
    const size_t pbase = (size_t)b * 2 * PLANE;

    float u[RPW][4], pD[RPW][4], pR[RPW][4];

    #pragma unroll
    for (int dr = 0; dr < RPW; ++dr) {
        const int grow = growbase + dr;
        const bool inimg = (grow >= 0) && (grow < HH);
        int dist = 0;
        if (grow < r0)                 dist = r0 - grow;
        else if (grow > r0 + CORE - 1) dist = grow - (r0 + CORE - 1);
        const bool needU = inimg && (dist <= ls);
        const bool needP = inimg && (dist < ls);   // params only for rows that compute

        if (needU) {
            const float4 uu = *reinterpret_cast<const float4*>(uin + ubase + (size_t)grow * WW + c0);
            u[dr][0] = uu.x; u[dr][1] = uu.y; u[dr][2] = uu.z; u[dr][3] = uu.w;
        } else {
            u[dr][0] = u[dr][1] = u[dr][2] = u[dr][3] = 0.f;
        }
        if (needP) {
            const float4 dd = *reinterpret_cast<const float4*>(params + pbase + (size_t)grow * WW + c0);
            const float4 rr = *reinterpret_cast<const float4*>(params + pbase + PLANE + (size_t)grow * WW + c0);
            pD[dr][0] = dd.x; pD[dr][1] = dd.y; pD[dr][2] = dd.z; pD[dr][3] = dd.w;
            pR[dr][0] = rr.x; pR[dr][1] = rr.y; pR[dr][2] = rr.z; pR[dr][3] = rr.w;
        } else {
            pD[dr][0] = pD[dr][1] = pD[dr][2] = pD[dr][3] = 0.f;
            pR[dr][0] = pR[dr][1] = pR[dr][2] = pR[dr][3] = 0.f;
        }
    }

    if (ls > 0) {
        // publish initial wave-boundary rows into buffer 0 (all waves)
        vt[0][w][lane] = make_float4(u[0][0], u[0][1], u[0][2], u[0][3]);
        vb[0][w][lane] = make_float4(u[RPW-1][0], u[RPW-1][1], u[RPW-1][2], u[RPW-1][3]);

        for (int s = 0; s < ls; ++s) {
            __syncthreads();                 // buf[s&1] now visible to all waves
            if (s < my_steps) {              // wave-uniform trapezoid skip
                const int cur = s & 1;

                float upr[4] = {0.f, 0.f, 0.f, 0.f};
                float dnr[4] = {0.f, 0.f, 0.f, 0.f};
                if (w > 0)      { float4 v = vb[cur][w-1][lane]; upr[0]=v.x; upr[1]=v.y; upr[2]=v.z; upr[3]=v.w; }
                if (w < NW - 1) { float4 v = vt[cur][w+1][lane]; dnr[0]=v.x; dnr[1]=v.y; dnr[2]=v.z; dnr[3]=v.w; }

                float up_old[4];             // old value of row dr-1 (rolling carry)
                #pragma unroll
                for (int dr = 0; dr < RPW; ++dr) {
                    // horizontal neighbors via DPP (VALU pipe, border zero-fill free)
                    const float lf = dpp_shfl_up1(u[dr][3]);
                    const float rt = dpp_shfl_dn1(u[dr][0]);

                    float old[4], un[4];
                    #pragma unroll
                    for (int c = 0; c < 4; ++c) old[c] = u[dr][c];

                    #pragma unroll
                    for (int c = 0; c < 4; ++c) {
                        const float upv = dr ? up_old[c] : upr[c];
                        const float dnv = (dr < RPW - 1) ? u[dr+1][c] : dnr[c];
                        const float lv  = c ? old[c-1] : lf;
                        const float rv  = (c < 3) ? old[c+1] : rt;
                        const float uc  = old[c];
                        const float s4  = (upv + dnv) + (lv + rv);
                        const float lap = fmaf(-4.0f, uc, s4);
                        const float g   = fmaf(-uc, uc, uc);          // uc*(1-uc)
                        const float a   = fmaf(pD[dr][c], lap, uc);
                        const float nv  = fmaf(pR[dr][c], g, a);
                        un[c] = __builtin_amdgcn_fmed3f(nv, 0.0f, 1.0f);
                    }
                    #pragma unroll
                    for (int c = 0; c < 4; ++c) { u[dr][c] = un[c]; up_old[c] = old[c]; }
                }

                const int nxt = cur ^ 1;
                vt[nxt][w][lane] = make_float4(u[0][0], u[0][1], u[0][2], u[0][3]);
                vb[nxt][w][lane] = make_float4(u[RPW-1][0], u[RPW-1][1], u[RPW-1][2], u[RPW-1][3]);
            }
        }
    }

    // write back the 16-row core (per-row predicate; slab rows 16..31)
    #pragma unroll
    for (int dr = 0; dr < RPW; ++dr) {
        const int grow = growbase + dr;
        if (grow >= r0 && grow < r0 + CORE) {
            *reinterpret_cast<float4*>(uout + ubase + (size_t)grow * WW + c0) =
                make_float4(u[dr][0], u[dr][1], u[dr][2], u[dr][3]);
        }
    }
}

extern "C" void kernel_launch(void* const* d_in, const int* in_sizes, int n_in,
                              void* d_out, int out_size, void* d_ws, size_t ws_size,
                              hipStream_t stream) {
    (void)in_sizes; (void)n_in; (void)out_size; (void)ws_size;
    const float* u      = (const float*)d_in[0];
    const float* params = (const float*)d_in[1];
    const int*   t      = (const int*)d_in[2];
    float*       out    = (float*)d_out;
    float*       ws     = (float*)d_ws;

    const dim3 grid(512), block(1024);
    // steps [0,16) -> ws, steps [16,31) -> out
    rd_occ_kernel<<<grid, block, 0, stream>>>(u,  params, t, ws,  0,  16);
    rd_occ_kernel<<<grid, block, 0, stream>>>(ws, params, t, out, 16, 15);
}